// Round 9
// baseline (951.469 us; speedup 1.0000x reference)
//
#include <hip/hip_runtime.h>
#include <hip/hip_bf16.h>

typedef unsigned short u16;
typedef __attribute__((ext_vector_type(8))) short short8;
typedef __attribute__((ext_vector_type(4))) float f32x4;
typedef __attribute__((ext_vector_type(16))) float f32x16;

__device__ inline u16 f2bf(float f) {
  unsigned u = __float_as_uint(f);
  u += 0x7fffu + ((u >> 16) & 1u);   // round-to-nearest-even
  return (u16)(u >> 16);
}

// ---------------- fused prep: cast x + transpose-cast both weights ----------------
__global__ __launch_bounds__(256) void prep_kernel(const float* __restrict__ x,
                                                   u16* __restrict__ xb,
                                                   const float* __restrict__ wq,
                                                   u16* __restrict__ wqT,
                                                   const float* __restrict__ wp,
                                                   u16* __restrict__ wpT) {
  __shared__ float tile[32][33];
  int bid = blockIdx.x;
  if (bid < 8192) {
    int i = bid * 256 + threadIdx.x;
    float4 v = ((const float4*)x)[i];
    ushort4 o;
    o.x = f2bf(v.x); o.y = f2bf(v.y); o.z = f2bf(v.z); o.w = f2bf(v.w);
    ((ushort4*)xb)[i] = o;
    return;
  }
  const float* in; u16* out; int N, bx, by;
  if (bid < 11264) {
    int idx = bid - 8192;
    in = wq; out = wqT; N = 3072;
    bx = (idx % 96) * 32; by = (idx / 96) * 32;
  } else {
    int idx = bid - 11264;
    in = wp; out = wpT; N = 1024;
    bx = (idx % 32) * 32; by = (idx / 32) * 32;
  }
  int tx = threadIdx.x & 31, ty = threadIdx.x >> 5;
#pragma unroll
  for (int i = 0; i < 4; i++) {
    int r = ty + i * 8;
    tile[r][tx] = in[(size_t)(by + r) * N + bx + tx];
  }
  __syncthreads();
#pragma unroll
  for (int i = 0; i < 4; i++) {
    int r = ty + i * 8;
    out[(size_t)(bx + r) * 1024 + by + tx] = f2bf(tile[tx][r]);
  }
}

// ==================== gemm_qkv: 256x256, BK=32, 64KB LDS, 2 blocks/CU ==============
// TLP-first redesign: 2 buffers x (A 16KB | B 16KB) = 64KB -> 2 co-resident blocks
// per CU; all 384 blocks run in ONE round, and the partner block's waves hide this
// block's barrier/latency stalls (m114 principle). Schedule = round-8 verified
// single-barrier phase skeleton at BK=32 (2 phases/tile, 32 tiles):
//   P1(T): stage A(T+1); vm(4); BAR; read a[8]@T; lgkm0; 16 MFMA (n01, cur)
//   P2(T): stage B(T+2); vm(4); BAR; read b[4]@T+1 (nxt); lgkm0; 16 MFMA (n23, cur)
// Queue order {A(T), B(T+1), new}: vm(4) retires exactly the region read after BAR.
// WAR: each region's last reads drain at lgkm0 >=1 barrier before its re-stage.
// Prologue A0,B0,B1 + vm(2); tail vm(2)@P2(30), vm(0)@P1(31).
#define VMWAIT(n) asm volatile("s_waitcnt vmcnt(" #n ")" ::: "memory")
#define LGKM0() asm volatile("s_waitcnt lgkmcnt(0)" ::: "memory")
#define BAR() asm volatile("s_barrier" ::: "memory")

__device__ __forceinline__ void gll16(const u16* g, u16* l) {
  __builtin_amdgcn_global_load_lds((const __attribute__((address_space(1))) unsigned*)g,
                                   (__attribute__((address_space(3))) unsigned*)l, 16, 0, 0);
}

__global__ __launch_bounds__(512, 4) void gemm_qkv(const u16* __restrict__ A,
                                                   const u16* __restrict__ Bt,
                                                   u16* __restrict__ qb,
                                                   u16* __restrict__ kpack,
                                                   u16* __restrict__ vpack) {
  __shared__ u16 lds[32768];  // 64 KB: buffer b at b*16384 u16 (A at +0, B at +8192)
  int tid = threadIdx.x;
  int w = tid >> 6, lane = tid & 63, l15 = lane & 15, quad = lane >> 4;
  int wr = w >> 2, wc = w & 3;

  int bid = blockIdx.x;
  int wgid = (bid & 7) * 48 + (bid >> 3);
  int bm = (wgid / 12) * 256;
  int bn3 = (wgid % 12) * 256;

  int srow = lane >> 2;
  int kswz = ((lane & 3) * 8) ^ ((lane >> 5) << 4);  // in [0,32)
  const u16* gA0 = A + (size_t)(bm + w * 16 + srow) * 1024 + kswz;
  const u16* gA1 = A + (size_t)(bm + 128 + w * 16 + srow) * 1024 + kswz;
  const u16* gB0 = Bt + (size_t)(bn3 + w * 16 + srow) * 1024 + kswz;
  const u16* gB1 = Bt + (size_t)(bn3 + 128 + w * 16 + srow) * 1024 + kswz;

  int kq = (quad * 8) ^ ((l15 & 8) << 1);  // in [0,32)
  int aoff = wr * 4096 + l15 * 32 + kq;            // + m*512, m in [0,8)
  int boff = 8192 + wc * 2048 + l15 * 32 + kq;     // + n*512, n in [0,4)

  f32x4 acc[8][4];
#pragma unroll
  for (int m = 0; m < 8; m++)
#pragma unroll
    for (int n = 0; n < 4; n++) acc[m][n] = (f32x4)0.0f;

  short8 a[8], bA[4], bB[4];

#define STAGE_A(T)                                            \
  do {                                                        \
    u16* d_ = lds + ((T) & 1) * 16384 + w * 512;              \
    gll16(gA0 + (size_t)(T) * 32, d_);                        \
    gll16(gA1 + (size_t)(T) * 32, d_ + 4096);                 \
  } while (0)
#define STAGE_B(T)                                            \
  do {                                                        \
    u16* d_ = lds + ((T) & 1) * 16384 + 8192 + w * 512;       \
    gll16(gB0 + (size_t)(T) * 32, d_);                        \
    gll16(gB1 + (size_t)(T) * 32, d_ + 4096);                 \
  } while (0)

#define MFMA16(NLO, BV0, BV1)                                                                  \
  do {                                                                                         \
    __builtin_amdgcn_s_setprio(1);                                                             \
    _Pragma("unroll") for (int m = 0; m < 8; m++)                                              \
        acc[m][NLO] = __builtin_amdgcn_mfma_f32_16x16x32_bf16(a[m], BV0, acc[m][NLO], 0, 0, 0);\
    _Pragma("unroll") for (int m = 0; m < 8; m++)                                              \
        acc[m][NLO + 1] =                                                                      \
            __builtin_amdgcn_mfma_f32_16x16x32_bf16(a[m], BV1, acc[m][NLO + 1], 0, 0, 0);      \
    __builtin_amdgcn_s_setprio(0);                                                             \
  } while (0)

// P1(T): stage A(T+1); vm; BAR; read a[8]@T; lgkm0; MFMA n01 with cur
#define PHASE1(T, cur, DOSTG, VMN)                                                             \
  do {                                                                                         \
    if (DOSTG) STAGE_A((T) + 1);                                                               \
    VMN;                                                                                       \
    BAR();                                                                                     \
    const u16* bc_ = lds + ((T) & 1) * 16384;                                                  \
    _Pragma("unroll") for (int m = 0; m < 8; m++)                                              \
        a[m] = *(const short8*)(bc_ + aoff + m * 512);                                         \
    LGKM0();                                                                                   \
    MFMA16(0, cur[0], cur[1]);                                                                 \
  } while (0)

// P2(T): stage B(T+2); vm; BAR; read nxt[4] = b@T+1; lgkm0; MFMA n23 with cur
#define PHASE2(T, cur, nxt, DORD, DOSTG, VMN)                                                  \
  do {                                                                                         \
    if (DOSTG) STAGE_B((T) + 2);                                                               \
    VMN;                                                                                       \
    BAR();                                                                                     \
    if (DORD) {                                                                                \
      const u16* bn_ = lds + (((T) + 1) & 1) * 16384;                                          \
      _Pragma("unroll") for (int n = 0; n < 4; n++)                                            \
          nxt[n] = *(const short8*)(bn_ + boff + n * 512);                                     \
    }                                                                                          \
    LGKM0();                                                                                   \
    MFMA16(2, cur[2], cur[3]);                                                                 \
  } while (0)

  // prologue: A(0), B(0), B(1); vm(2) retires A(0)+B(0), keeps B(1); pre-read bA@0
  STAGE_A(0); STAGE_B(0); STAGE_B(1);
  VMWAIT(2);
  BAR();
  {
    const u16* bc_ = lds;
#pragma unroll
    for (int n = 0; n < 4; n++) bA[n] = *(const short8*)(bc_ + boff + n * 512);
  }

  // main loop: tiles 0..29 (unroll x2 for bA/bB parity)
  for (int T = 0; T < 30; T += 2) {
    PHASE1(T, bA, 1, VMWAIT(4));
    PHASE2(T, bA, bB, 1, 1, VMWAIT(4));
    PHASE1(T + 1, bB, 1, VMWAIT(4));
    PHASE2(T + 1, bB, bA, 1, 1, VMWAIT(4));
  }
  // tail: T=30 (B-stage off), T=31 (all off, drain)
  PHASE1(30, bA, 1, VMWAIT(4));        // stages A(31)
  PHASE2(30, bA, bB, 1, 0, VMWAIT(2)); // retires B(31), keeps A(31)
  PHASE1(31, bB, 0, VMWAIT(0));        // drains A(31)
  PHASE2(31, bB, bA, 0, 0, (void)0);

#undef PHASE1
#undef PHASE2
#undef MFMA16
#undef STAGE_A
#undef STAGE_B

  if (bn3 < 1024) {
    float scl = 0.18033688011112f;
    int rbase = bm + wr * 128 + quad * 4;
    int cbase = bn3 + wc * 64 + l15;
#pragma unroll
    for (int m = 0; m < 8; m++)
#pragma unroll
      for (int n = 0; n < 4; n++)
#pragma unroll
        for (int r = 0; r < 4; r++)
          qb[(size_t)(rbase + m * 16 + r) * 1024 + cbase + n * 16] = f2bf(acc[m][n][r] * scl);
  } else {
    int bnl = bn3 & 1023;
    int h = (bnl >> 6) + wc;
    int bh = (bm >> 11) * 16 + h;
    int ktb = ((bm & 2047) >> 6) + wr * 2;
    if (bn3 < 2048) {
      int lhi = ((l15 >> 3) & 1) * 32;
      int e = l15 & 7;
#pragma unroll
      for (int m = 0; m < 8; m++) {
        u16* kd = kpack + ((size_t)bh * 32 + ktb + (m >> 2)) * 4096;
        int krb = (m & 3) * 16 + quad * 4;
        int jm = (krb >> 5) * 4;
        int l31b = krb & 31;
#pragma unroll
        for (int n = 0; n < 4; n++)
#pragma unroll
          for (int r = 0; r < 4; r++) {
            int off = (jm + n) * 512 + (l31b + r + lhi) * 8 + e;
            kd[off] = f2bf(acc[m][n][r]);
          }
      }
    } else {
      int e0 = (quad & 1) * 4;
      int hi5 = (quad >> 1) * 32;
#pragma unroll
      for (int m = 0; m < 8; m++) {
        u16* vd = vpack + ((size_t)bh * 32 + ktb + (m >> 2)) * 4096;
#pragma unroll
        for (int n = 0; n < 4; n++) {
          int off = ((n >> 1) * 4 + (m & 3)) * 512 +
                    ((n & 1) * 16 + l15 + hi5) * 8 + e0;
          ushort4 wv;
          wv.x = f2bf(acc[m][n][0]);
          wv.y = f2bf(acc[m][n][1]);
          wv.z = f2bf(acc[m][n][2]);
          wv.w = f2bf(acc[m][n][3]);
          *(ushort4*)(vd + off) = wv;
        }
      }
    }
  }
}

// ==================== gemm_proj: 256x128, BK=64, SINGLE-BARRIER (round-8 verified) ==
__global__ __launch_bounds__(512, 2) void gemm_proj(const u16* __restrict__ A,
                                                    const u16* __restrict__ Bt,
                                                    float* __restrict__ Co) {
  __shared__ u16 lds[49152];  // 96 KB
  int tid = threadIdx.x;
  int w = tid >> 6, lane = tid & 63, l15 = lane & 15, quad = lane >> 4;
  int wr = w >> 1, wc = w & 1;

  int bid = blockIdx.x;
  int wgid = (bid & 7) * 32 + (bid >> 3);
  int bm = (wgid >> 3) * 256;
  int bn = (wgid & 7) * 128;

  int srow = lane >> 2;
  int kswz = ((lane & 3) * 8) ^ ((lane >> 5) << 4);
  const u16* gA0 = A + (size_t)(bm + w * 16 + srow) * 1024 + kswz;
  const u16* gA1 = A + (size_t)(bm + 128 + w * 16 + srow) * 1024 + kswz;
  const u16* gB0 = Bt + (size_t)(bn + w * 16 + srow) * 1024 + kswz;

  int kq = (quad * 8) ^ ((l15 & 8) << 1);
  int aoff = (wr >> 1) * 8192 + (wr & 1) * 2048 + l15 * 32 + kq;
  int boff = 16384 + wc * 2048 + l15 * 32 + kq;

  f32x4 acc[4][4];
#pragma unroll
  for (int m = 0; m < 4; m++)
#pragma unroll
    for (int n = 0; n < 4; n++) acc[m][n] = (f32x4)0.0f;

  short8 a[4], bA[4], bB[4];

#define PSTG_ALO(T)                                           \
  do {                                                        \
    u16* d_ = lds + ((T) & 1) * 24576 + w * 512;              \
    gll16(gA0 + (size_t)(T) * 64, d_);                        \
    gll16(gA0 + (size_t)(T) * 64 + 32, d_ + 4096);            \
  } while (0)
#define PSTG_AHI(T)                                           \
  do {                                                        \
    u16* d_ = lds + ((T) & 1) * 24576 + 8192 + w * 512;       \
    gll16(gA1 + (size_t)(T) * 64, d_);                        \
    gll16(gA1 + (size_t)(T) * 64 + 32, d_ + 4096);            \
  } while (0)
#define PSTG_B(T)                                             \
  do {                                                        \
    u16* d_ = lds + ((T) & 1) * 24576 + 16384 + w * 512;      \
    gll16(gB0 + (size_t)(T) * 64, d_);                        \
    gll16(gB0 + (size_t)(T) * 64 + 32, d_ + 4096);            \
  } while (0)

#define MFMA8(NLO, BV0, BV1)                                                                   \
  do {                                                                                         \
    __builtin_amdgcn_s_setprio(1);                                                             \
    _Pragma("unroll") for (int m = 0; m < 4; m++)                                              \
        acc[m][NLO] = __builtin_amdgcn_mfma_f32_16x16x32_bf16(a[m], BV0, acc[m][NLO], 0, 0, 0);\
    _Pragma("unroll") for (int m = 0; m < 4; m++)                                              \
        acc[m][NLO + 1] =                                                                      \
            __builtin_amdgcn_mfma_f32_16x16x32_bf16(a[m], BV1, acc[m][NLO + 1], 0, 0, 0);      \
    __builtin_amdgcn_s_setprio(0);                                                             \
  } while (0)

#define PPH1(T, DOSTG, VMN)                                                                    \
  do {                                                                                         \
    if (DOSTG) PSTG_ALO((T) + 1);                                                              \
    VMN;                                                                                       \
    BAR();                                                                                     \
    const u16* bc_ = lds + ((T) & 1) * 24576;                                                  \
    _Pragma("unroll") for (int m = 0; m < 4; m++)                                              \
        a[m] = *(const short8*)(bc_ + aoff + m * 512);                                         \
    LGKM0();                                                                                   \
    MFMA8(0, bA[0], bA[1]);                                                                    \
  } while (0)

#define PPH2(T, DOSTG)                                                                         \
  do {                                                                                         \
    if (DOSTG) PSTG_AHI((T) + 1);                                                              \
    BAR();                                                                                     \
    const u16* bc_ = lds + ((T) & 1) * 24576;                                                  \
    _Pragma("unroll") for (int n = 0; n < 4; n++)                                              \
        bB[n] = *(const short8*)(bc_ + boff + 4096 + n * 512);                                 \
    LGKM0();                                                                                   \
    MFMA8(2, bA[2], bA[3]);                                                                    \
  } while (0)

#define PPH3(T)                                                                                \
  do {                                                                                         \
    BAR();                                                                                     \
    const u16* bc_ = lds + ((T) & 1) * 24576;                                                  \
    _Pragma("unroll") for (int m = 0; m < 4; m++)                                              \
        a[m] = *(const short8*)(bc_ + aoff + 4096 + m * 512);                                  \
    LGKM0();                                                                                   \
    MFMA8(0, bB[0], bB[1]);                                                                    \
  } while (0)

#define PPH4(T, DOSTG, DORD, VMN)                                                              \
  do {                                                                                         \
    if (DOSTG) PSTG_B((T) + 2);                                                                \
    VMN;                                                                                       \
    BAR();                                                                                     \
    if (DORD) {                                                                                \
      const u16* bn_ = lds + (((T) + 1) & 1) * 24576;                                          \
      _Pragma("unroll") for (int n = 0; n < 4; n++)                                            \
          bA[n] = *(const short8*)(bn_ + boff + n * 512);                                      \
    }                                                                                          \
    LGKM0();                                                                                   \
    MFMA8(2, bB[2], bB[3]);                                                                    \
  } while (0)

  PSTG_B(0); PSTG_ALO(0); PSTG_AHI(0); PSTG_B(1);
  VMWAIT(2);
  BAR();
  {
    const u16* bc_ = lds;
#pragma unroll
    for (int n = 0; n < 4; n++) bA[n] = *(const short8*)(bc_ + boff + n * 512);
  }

  for (int T = 0; T < 14; ++T) {
    PPH1(T, 1, VMWAIT(4));
    PPH2(T, 1);
    PPH3(T);
    PPH4(T, 1, 1, VMWAIT(6));
  }
  PPH1(14, 1, VMWAIT(4));
  PPH2(14, 1);
  PPH3(14);
  PPH4(14, 0, 1, VMWAIT(4));
  PPH1(15, 0, VMWAIT(0));
  PPH2(15, 0);
  PPH3(15);
  PPH4(15, 0, 0, (void)0);

#undef PPH1
#undef PPH2
#undef PPH3
#undef PPH4
#undef MFMA8
#undef PSTG_ALO
#undef PSTG_AHI
#undef PSTG_B

  int rbase = bm + wr * 64 + quad * 4;
  int cbase = bn + wc * 64 + l15;
#pragma unroll
  for (int m = 0; m < 4; m++)
#pragma unroll
    for (int n = 0; n < 4; n++)
#pragma unroll
      for (int r = 0; r < 4; r++)
        Co[(size_t)(rbase + m * 16 + r) * 1024 + cbase + n * 16] = acc[m][n][r];
}

// ---------------- flash attention (verified, unchanged) ----------------
__global__ __launch_bounds__(256, 2) void attn_kernel(const u16* __restrict__ qbuf,
                                                      const u16* __restrict__ kpack,
                                                      const u16* __restrict__ vpack,
                                                      u16* __restrict__ ctx) {
  int t = threadIdx.x;
  int wave = t >> 6, lane = t & 63, l31 = lane & 31, hi = lane >> 5;
  int bh = blockIdx.x;
  int s = (int)blockIdx.y * 4 + wave;
  int b = bh >> 4, h = bh & 15;
  int rowbase = b * 2048;
  int hi4 = hi * 4;

  const u16* kp = kpack + (size_t)bh * (32 * 4096) + lane * 8;
  const u16* vp = vpack + (size_t)bh * (32 * 4096) + lane * 8;

#pragma unroll
  for (int ph = 0; ph < 2; ph++) {
    int strip = ph ? 63 - s : s;
    int q0 = strip * 32;
    int q_lane = q0 + l31;

    const u16* qp = qbuf + (size_t)(rowbase + q_lane) * 1024 + h * 64 + hi * 8;
    short8 qf[4];
#pragma unroll
    for (int ks = 0; ks < 4; ks++) qf[ks] = *(const short8*)(qp + ks * 16);

    float l_run = 0.0f;
    f32x16 o[2];
    o[0] = (f32x16)0.0f; o[1] = (f32x16)0.0f;
    int ktmax = (q0 + 31) >> 6;

    for (int kt = 0; kt <= ktmax; kt++) {
      const u16* kb = kp + kt * 4096;
      const u16* vb = vp + kt * 4096;

      short8 ka[8], vv[8];
#pragma unroll
      for (int j = 0; j < 8; j++) {
        ka[j] = *(const short8*)(kb + j * 512);
        vv[j] = *(const short8*)(vb + j * 512);
      }

      f32x16 st0 = (f32x16)0.0f, st1 = (f32x16)0.0f;
#pragma unroll
      for (int ks = 0; ks < 4; ks++) {
        st0 = __builtin_amdgcn_mfma_f32_32x32x16_bf16(ka[ks], qf[ks], st0, 0, 0, 0);
        st1 = __builtin_amdgcn_mfma_f32_32x32x16_bf16(ka[4 + ks], qf[ks], st1, 0, 0, 0);
      }

      unsigned pk[2][8];
      if (kt == ktmax) {
#pragma unroll
        for (int ii = 0; ii < 8; ii++) {
          int key = kt * 64 + ((2 * ii) & 3) + 8 * ((2 * ii) >> 2) + hi4;
          float p00 = (key     <= q_lane) ? __builtin_amdgcn_exp2f(st0[2 * ii])     : 0.0f;
          float p01 = (key + 1 <= q_lane) ? __builtin_amdgcn_exp2f(st0[2 * ii + 1]) : 0.0f;
          float p10 = (key + 32 <= q_lane) ? __builtin_amdgcn_exp2f(st1[2 * ii])     : 0.0f;
          float p11 = (key + 33 <= q_lane) ? __builtin_amdgcn_exp2f(st1[2 * ii + 1]) : 0.0f;
          l_run += p00 + p01 + p10 + p11;
          pk[0][ii] = ((__float_as_uint(p00) + 0x8000u) >> 16) |
                      ((__float_as_uint(p01) + 0x8000u) & 0xffff0000u);
          pk[1][ii] = ((__float_as_uint(p10) + 0x8000u) >> 16) |
                      ((__float_as_uint(p11) + 0x8000u) & 0xffff0000u);
        }
      } else {
#pragma unroll
        for (int ii = 0; ii < 8; ii++) {
          float p00 = __builtin_amdgcn_exp2f(st0[2 * ii]);
          float p01 = __builtin_amdgcn_exp2f(st0[2 * ii + 1]);
          float p10 = __builtin_amdgcn_exp2f(st1[2 * ii]);
          float p11 = __builtin_amdgcn_exp2f(st1[2 * ii + 1]);
          l_run += p00 + p01 + p10 + p11;
          pk[0][ii] = ((__float_as_uint(p00) + 0x8000u) >> 16) |
                      ((__float_as_uint(p01) + 0x8000u) & 0xffff0000u);
          pk[1][ii] = ((__float_as_uint(p10) + 0x8000u) >> 16) |
                      ((__float_as_uint(p11) + 0x8000u) & 0xffff0000u);
        }
      }

      short8 pf[4];
#pragma unroll
      for (int ks2 = 0; ks2 < 4; ks2++) {
        int km = ks2 >> 1, h4 = (ks2 & 1) * 4;
        unsigned A0 = pk[km][h4 + 0], A1 = pk[km][h4 + 1];
        unsigned B0 = pk[km][h4 + 2], B1 = pk[km][h4 + 3];
        unsigned tA0 = (unsigned)__shfl_xor((int)A0, 32);
        unsigned tA1 = (unsigned)__shfl_xor((int)A1, 32);
        unsigned tB0 = (unsigned)__shfl_xor((int)B0, 32);
        unsigned tB1 = (unsigned)__shfl_xor((int)B1, 32);
        union { unsigned u[4]; short8 sh; } fr;
        fr.u[0] = hi ? tB0 : A0;
        fr.u[1] = hi ? tB1 : A1;
        fr.u[2] = hi ? B0 : tA0;
        fr.u[3] = hi ? B1 : tA1;
        pf[ks2] = fr.sh;
      }

#pragma unroll
      for (int am = 0; am < 2; am++)
#pragma unroll
        for (int ks2 = 0; ks2 < 4; ks2++)
          o[am] = __builtin_amdgcn_mfma_f32_32x32x16_bf16(vv[am * 4 + ks2], pf[ks2], o[am], 0, 0, 0);
    }

    float l_tot = l_run + __shfl_xor(l_run, 32);
    float inv = 1.0f / l_tot;
    size_t obase = (size_t)(rowbase + q_lane) * 1024 + h * 64;
#pragma unroll
    for (int am = 0; am < 2; am++)
#pragma unroll
      for (int k = 0; k < 4; k++) {
        ushort4 w;
        w.x = f2bf(o[am][4 * k + 0] * inv);
        w.y = f2bf(o[am][4 * k + 1] * inv);
        w.z = f2bf(o[am][4 * k + 2] * inv);
        w.w = f2bf(o[am][4 * k + 3] * inv);
        *(ushort4*)&ctx[obase + am * 32 + k * 8 + hi4] = w;
      }
  }
}

// ---------------- launch ----------------
extern "C" void kernel_launch(void* const* d_in, const int* in_sizes, int n_in,
                              void* d_out, int out_size, void* d_ws, size_t ws_size,
                              hipStream_t stream) {
  const float* x      = (const float*)d_in[0];
  const float* w_qkv  = (const float*)d_in[1];
  const float* w_proj = (const float*)d_in[2];
  float* out = (float*)d_out;

  char* ws = (char*)d_ws;
  const size_t MB = 1024 * 1024;
  u16* qbuf   = (u16*)(ws);
  u16* kpack  = (u16*)(ws + 16 * MB);
  u16* vpack  = (u16*)(ws + 32 * MB);
  u16* xb     = (u16*)(ws + 48 * MB);
  u16* ctx    = (u16*)(ws + 64 * MB);
  u16* wqkvT  = (u16*)(ws + 80 * MB);
  u16* wprojT = (u16*)(ws + 86 * MB);

  prep_kernel<<<12288, 256, 0, stream>>>(x, xb, w_qkv, wqkvT, w_proj, wprojT);
  gemm_qkv<<<dim3(384), 512, 0, stream>>>(xb, wqkvT, qbuf, kpack, vpack);
  attn_kernel<<<dim3(64, 8), 256, 0, stream>>>(qbuf, kpack, vpack, ctx);
  gemm_proj<<<dim3(256), 512, 0, stream>>>(ctx, wprojT, out);
}

// Round 10
// 225.461 us; speedup vs baseline: 4.2201x; 4.2201x over previous
//
#include <hip/hip_runtime.h>
#include <hip/hip_bf16.h>

typedef unsigned short u16;
typedef __attribute__((ext_vector_type(8))) short short8;
typedef __attribute__((ext_vector_type(4))) float f32x4;
typedef __attribute__((ext_vector_type(16))) float f32x16;

__device__ inline u16 f2bf(float f) {
  unsigned u = __float_as_uint(f);
  u += 0x7fffu + ((u >> 16) & 1u);   // round-to-nearest-even
  return (u16)(u >> 16);
}

// ---------------- fused prep: cast x + transpose-cast both weights ----------------
__global__ __launch_bounds__(256) void prep_kernel(const float* __restrict__ x,
                                                   u16* __restrict__ xb,
                                                   const float* __restrict__ wq,
                                                   u16* __restrict__ wqT,
                                                   const float* __restrict__ wp,
                                                   u16* __restrict__ wpT) {
  __shared__ float tile[32][33];
  int bid = blockIdx.x;
  if (bid < 8192) {
    int i = bid * 256 + threadIdx.x;
    float4 v = ((const float4*)x)[i];
    ushort4 o;
    o.x = f2bf(v.x); o.y = f2bf(v.y); o.z = f2bf(v.z); o.w = f2bf(v.w);
    ((ushort4*)xb)[i] = o;
    return;
  }
  const float* in; u16* out; int N, bx, by;
  if (bid < 11264) {
    int idx = bid - 8192;
    in = wq; out = wqT; N = 3072;
    bx = (idx % 96) * 32; by = (idx / 96) * 32;
  } else {
    int idx = bid - 11264;
    in = wp; out = wpT; N = 1024;
    bx = (idx % 32) * 32; by = (idx / 32) * 32;
  }
  int tx = threadIdx.x & 31, ty = threadIdx.x >> 5;
#pragma unroll
  for (int i = 0; i < 4; i++) {
    int r = ty + i * 8;
    tile[r][tx] = in[(size_t)(by + r) * N + bx + tx];
  }
  __syncthreads();
#pragma unroll
  for (int i = 0; i < 4; i++) {
    int r = ty + i * 8;
    out[(size_t)(bx + r) * 1024 + by + tx] = f2bf(tile[tx][r]);
  }
}

// ==================== gemm_qkv: 256x256, BK=64, SINGLE-BARRIER (round-8 verified) ===
// REVERTED byte-exact to round 8 (68 us, VGPR 128). Round 9's launch_bounds(512,4)
// starved the register file (64 VGPR) and spilled the 128-reg accumulator to
// scratch (FETCH 59MB -> 1.28GB). A 256^2/8-wave tile pins ~256 regs/wave ->
// 2 waves/SIMD is the HW max; higher-occupancy variants need a smaller tile,
// which round-0 already measured equal (71 us). GEMM is at its plateau.
#define VMWAIT(n) asm volatile("s_waitcnt vmcnt(" #n ")" ::: "memory")
#define LGKM0() asm volatile("s_waitcnt lgkmcnt(0)" ::: "memory")
#define BAR() asm volatile("s_barrier" ::: "memory")

__device__ __forceinline__ void gll16(const u16* g, u16* l) {
  __builtin_amdgcn_global_load_lds((const __attribute__((address_space(1))) unsigned*)g,
                                   (__attribute__((address_space(3))) unsigned*)l, 16, 0, 0);
}

__global__ __launch_bounds__(512, 2) void gemm_qkv(const u16* __restrict__ A,
                                                   const u16* __restrict__ Bt,
                                                   u16* __restrict__ qb,
                                                   u16* __restrict__ kpack,
                                                   u16* __restrict__ vpack) {
  __shared__ u16 lds[65536];  // 128 KB: buffer b at b*32768 u16
  int tid = threadIdx.x;
  int w = tid >> 6, lane = tid & 63, l15 = lane & 15, quad = lane >> 4;
  int wr = w >> 2, wc = w & 3;

  int bid = blockIdx.x;
  int wgid = (bid & 7) * 48 + (bid >> 3);
  int bm = (wgid / 12) * 256;
  int bn3 = (wgid % 12) * 256;

  int srow = lane >> 2;
  int kswz = ((lane & 3) * 8) ^ ((lane >> 5) << 4);
  const u16* gA0 = A + (size_t)(bm + w * 16 + srow) * 1024 + kswz;
  const u16* gA1 = A + (size_t)(bm + 128 + w * 16 + srow) * 1024 + kswz;
  const u16* gB0 = Bt + (size_t)(bn3 + w * 16 + srow) * 1024 + kswz;
  const u16* gB1 = Bt + (size_t)(bn3 + 128 + w * 16 + srow) * 1024 + kswz;

  int kq = (quad * 8) ^ ((l15 & 8) << 1);
  int aoff = wr * 8192 + l15 * 32 + kq;
  int boff = 16384 + (wc >> 1) * 8192 + (wc & 1) * 2048 + l15 * 32 + kq;

  f32x4 acc[8][4];
#pragma unroll
  for (int m = 0; m < 8; m++)
#pragma unroll
    for (int n = 0; n < 4; n++) acc[m][n] = (f32x4)0.0f;

  short8 a[8], bA[4], bB[4];

#define STAGE_AH0(T)                                          \
  do {                                                        \
    u16* d_ = lds + ((T) & 1) * 32768 + w * 512;              \
    gll16(gA0 + (size_t)(T) * 64, d_);                        \
    gll16(gA0 + (size_t)(T) * 64 + 32, d_ + 4096);            \
  } while (0)
#define STAGE_AH1(T)                                          \
  do {                                                        \
    u16* d_ = lds + ((T) & 1) * 32768 + 8192 + w * 512;       \
    gll16(gA1 + (size_t)(T) * 64, d_);                        \
    gll16(gA1 + (size_t)(T) * 64 + 32, d_ + 4096);            \
  } while (0)
#define STAGE_BH0(T)                                          \
  do {                                                        \
    u16* d_ = lds + ((T) & 1) * 32768 + 16384 + w * 512;      \
    gll16(gB0 + (size_t)(T) * 64, d_);                        \
    gll16(gB0 + (size_t)(T) * 64 + 32, d_ + 4096);            \
  } while (0)
#define STAGE_BH1(T)                                          \
  do {                                                        \
    u16* d_ = lds + ((T) & 1) * 32768 + 24576 + w * 512;      \
    gll16(gB1 + (size_t)(T) * 64, d_);                        \
    gll16(gB1 + (size_t)(T) * 64 + 32, d_ + 4096);            \
  } while (0)

#define MFMA16(NLO, BV0, BV1)                                                                  \
  do {                                                                                         \
    __builtin_amdgcn_s_setprio(1);                                                             \
    _Pragma("unroll") for (int m = 0; m < 8; m++)                                              \
        acc[m][NLO] = __builtin_amdgcn_mfma_f32_16x16x32_bf16(a[m], BV0, acc[m][NLO], 0, 0, 0);\
    _Pragma("unroll") for (int m = 0; m < 8; m++)                                              \
        acc[m][NLO + 1] =                                                                      \
            __builtin_amdgcn_mfma_f32_16x16x32_bf16(a[m], BV1, acc[m][NLO + 1], 0, 0, 0);      \
    __builtin_amdgcn_s_setprio(0);                                                             \
  } while (0)

#define PHASE1(T, DOSTG, VMN)                                                                  \
  do {                                                                                         \
    if (DOSTG) STAGE_AH0((T) + 1);                                                             \
    VMN;                                                                                       \
    BAR();                                                                                     \
    const u16* bc_ = lds + ((T) & 1) * 32768;                                                  \
    _Pragma("unroll") for (int m = 0; m < 8; m++)                                              \
        a[m] = *(const short8*)(bc_ + aoff + m * 512);                                         \
    LGKM0();                                                                                   \
    MFMA16(0, bA[0], bA[1]);                                                                   \
  } while (0)

#define PHASE2(T, DOSTG)                                                                       \
  do {                                                                                         \
    if (DOSTG) STAGE_AH1((T) + 1);                                                             \
    BAR();                                                                                     \
    const u16* bc_ = lds + ((T) & 1) * 32768;                                                  \
    _Pragma("unroll") for (int n = 0; n < 4; n++)                                              \
        bB[n] = *(const short8*)(bc_ + boff + 4096 + n * 512);                                 \
    LGKM0();                                                                                   \
    MFMA16(2, bA[2], bA[3]);                                                                   \
  } while (0)

#define PHASE3(T)                                                                              \
  do {                                                                                         \
    BAR();                                                                                     \
    const u16* bc_ = lds + ((T) & 1) * 32768;                                                  \
    _Pragma("unroll") for (int m = 0; m < 8; m++)                                              \
        a[m] = *(const short8*)(bc_ + aoff + 4096 + m * 512);                                  \
    LGKM0();                                                                                   \
    MFMA16(0, bB[0], bB[1]);                                                                   \
  } while (0)

#define PHASE4(T, DOSTG, DORD, VMN)                                                            \
  do {                                                                                         \
    if (DOSTG) { STAGE_BH0((T) + 2); STAGE_BH1((T) + 2); }                                     \
    VMN;                                                                                       \
    BAR();                                                                                     \
    if (DORD) {                                                                                \
      const u16* bn_ = lds + (((T) + 1) & 1) * 32768;                                          \
      _Pragma("unroll") for (int n = 0; n < 4; n++)                                            \
          bA[n] = *(const short8*)(bn_ + boff + n * 512);                                      \
    }                                                                                          \
    LGKM0();                                                                                   \
    MFMA16(2, bB[2], bB[3]);                                                                   \
  } while (0)

  STAGE_BH0(0); STAGE_BH1(0); STAGE_AH0(0); STAGE_AH1(0); STAGE_BH0(1); STAGE_BH1(1);
  VMWAIT(4);
  BAR();
  {
    const u16* bc_ = lds;
#pragma unroll
    for (int n = 0; n < 4; n++) bA[n] = *(const short8*)(bc_ + boff + n * 512);
  }

  for (int T = 0; T < 14; ++T) {
    PHASE1(T, 1, VMWAIT(6));
    PHASE2(T, 1);
    PHASE3(T);
    PHASE4(T, 1, 1, VMWAIT(8));
  }
  PHASE1(14, 1, VMWAIT(6));
  PHASE2(14, 1);
  PHASE3(14);
  PHASE4(14, 0, 1, VMWAIT(4));
  PHASE1(15, 0, VMWAIT(0));
  PHASE2(15, 0);
  PHASE3(15);
  PHASE4(15, 0, 0, (void)0);

#undef PHASE1
#undef PHASE2
#undef PHASE3
#undef PHASE4
#undef MFMA16
#undef STAGE_AH0
#undef STAGE_AH1
#undef STAGE_BH0
#undef STAGE_BH1

  if (bn3 < 1024) {
    float scl = 0.18033688011112f;
    int rbase = bm + wr * 128 + quad * 4;
    int cbase = bn3 + wc * 64 + l15;
#pragma unroll
    for (int m = 0; m < 8; m++)
#pragma unroll
      for (int n = 0; n < 4; n++)
#pragma unroll
        for (int r = 0; r < 4; r++)
          qb[(size_t)(rbase + m * 16 + r) * 1024 + cbase + n * 16] = f2bf(acc[m][n][r] * scl);
  } else {
    int bnl = bn3 & 1023;
    int h = (bnl >> 6) + wc;
    int bh = (bm >> 11) * 16 + h;
    int ktb = ((bm & 2047) >> 6) + wr * 2;
    if (bn3 < 2048) {
      int lhi = ((l15 >> 3) & 1) * 32;
      int e = l15 & 7;
#pragma unroll
      for (int m = 0; m < 8; m++) {
        u16* kd = kpack + ((size_t)bh * 32 + ktb + (m >> 2)) * 4096;
        int krb = (m & 3) * 16 + quad * 4;
        int jm = (krb >> 5) * 4;
        int l31b = krb & 31;
#pragma unroll
        for (int n = 0; n < 4; n++)
#pragma unroll
          for (int r = 0; r < 4; r++) {
            int off = (jm + n) * 512 + (l31b + r + lhi) * 8 + e;
            kd[off] = f2bf(acc[m][n][r]);
          }
      }
    } else {
      int e0 = (quad & 1) * 4;
      int hi5 = (quad >> 1) * 32;
#pragma unroll
      for (int m = 0; m < 8; m++) {
        u16* vd = vpack + ((size_t)bh * 32 + ktb + (m >> 2)) * 4096;
#pragma unroll
        for (int n = 0; n < 4; n++) {
          int off = ((n >> 1) * 4 + (m & 3)) * 512 +
                    ((n & 1) * 16 + l15 + hi5) * 8 + e0;
          ushort4 wv;
          wv.x = f2bf(acc[m][n][0]);
          wv.y = f2bf(acc[m][n][1]);
          wv.z = f2bf(acc[m][n][2]);
          wv.w = f2bf(acc[m][n][3]);
          *(ushort4*)(vd + off) = wv;
        }
      }
    }
  }
}

// ==================== gemm_proj: 256x128, BK=64, SINGLE-BARRIER (round-8 verified) ==
__global__ __launch_bounds__(512, 2) void gemm_proj(const u16* __restrict__ A,
                                                    const u16* __restrict__ Bt,
                                                    float* __restrict__ Co) {
  __shared__ u16 lds[49152];  // 96 KB
  int tid = threadIdx.x;
  int w = tid >> 6, lane = tid & 63, l15 = lane & 15, quad = lane >> 4;
  int wr = w >> 1, wc = w & 1;

  int bid = blockIdx.x;
  int wgid = (bid & 7) * 32 + (bid >> 3);
  int bm = (wgid >> 3) * 256;
  int bn = (wgid & 7) * 128;

  int srow = lane >> 2;
  int kswz = ((lane & 3) * 8) ^ ((lane >> 5) << 4);
  const u16* gA0 = A + (size_t)(bm + w * 16 + srow) * 1024 + kswz;
  const u16* gA1 = A + (size_t)(bm + 128 + w * 16 + srow) * 1024 + kswz;
  const u16* gB0 = Bt + (size_t)(bn + w * 16 + srow) * 1024 + kswz;

  int kq = (quad * 8) ^ ((l15 & 8) << 1);
  int aoff = (wr >> 1) * 8192 + (wr & 1) * 2048 + l15 * 32 + kq;
  int boff = 16384 + wc * 2048 + l15 * 32 + kq;

  f32x4 acc[4][4];
#pragma unroll
  for (int m = 0; m < 4; m++)
#pragma unroll
    for (int n = 0; n < 4; n++) acc[m][n] = (f32x4)0.0f;

  short8 a[4], bA[4], bB[4];

#define PSTG_ALO(T)                                           \
  do {                                                        \
    u16* d_ = lds + ((T) & 1) * 24576 + w * 512;              \
    gll16(gA0 + (size_t)(T) * 64, d_);                        \
    gll16(gA0 + (size_t)(T) * 64 + 32, d_ + 4096);            \
  } while (0)
#define PSTG_AHI(T)                                           \
  do {                                                        \
    u16* d_ = lds + ((T) & 1) * 24576 + 8192 + w * 512;       \
    gll16(gA1 + (size_t)(T) * 64, d_);                        \
    gll16(gA1 + (size_t)(T) * 64 + 32, d_ + 4096);            \
  } while (0)
#define PSTG_B(T)                                             \
  do {                                                        \
    u16* d_ = lds + ((T) & 1) * 24576 + 16384 + w * 512;      \
    gll16(gB0 + (size_t)(T) * 64, d_);                        \
    gll16(gB0 + (size_t)(T) * 64 + 32, d_ + 4096);            \
  } while (0)

#define MFMA8(NLO, BV0, BV1)                                                                   \
  do {                                                                                         \
    __builtin_amdgcn_s_setprio(1);                                                             \
    _Pragma("unroll") for (int m = 0; m < 4; m++)                                              \
        acc[m][NLO] = __builtin_amdgcn_mfma_f32_16x16x32_bf16(a[m], BV0, acc[m][NLO], 0, 0, 0);\
    _Pragma("unroll") for (int m = 0; m < 4; m++)                                              \
        acc[m][NLO + 1] =                                                                      \
            __builtin_amdgcn_mfma_f32_16x16x32_bf16(a[m], BV1, acc[m][NLO + 1], 0, 0, 0);      \
    __builtin_amdgcn_s_setprio(0);                                                             \
  } while (0)

#define PPH1(T, DOSTG, VMN)                                                                    \
  do {                                                                                         \
    if (DOSTG) PSTG_ALO((T) + 1);                                                              \
    VMN;                                                                                       \
    BAR();                                                                                     \
    const u16* bc_ = lds + ((T) & 1) * 24576;                                                  \
    _Pragma("unroll") for (int m = 0; m < 4; m++)                                              \
        a[m] = *(const short8*)(bc_ + aoff + m * 512);                                         \
    LGKM0();                                                                                   \
    MFMA8(0, bA[0], bA[1]);                                                                    \
  } while (0)

#define PPH2(T, DOSTG)                                                                         \
  do {                                                                                         \
    if (DOSTG) PSTG_AHI((T) + 1);                                                              \
    BAR();                                                                                     \
    const u16* bc_ = lds + ((T) & 1) * 24576;                                                  \
    _Pragma("unroll") for (int n = 0; n < 4; n++)                                              \
        bB[n] = *(const short8*)(bc_ + boff + 4096 + n * 512);                                 \
    LGKM0();                                                                                   \
    MFMA8(2, bA[2], bA[3]);                                                                    \
  } while (0)

#define PPH3(T)                                                                                \
  do {                                                                                         \
    BAR();                                                                                     \
    const u16* bc_ = lds + ((T) & 1) * 24576;                                                  \
    _Pragma("unroll") for (int m = 0; m < 4; m++)                                              \
        a[m] = *(const short8*)(bc_ + aoff + 4096 + m * 512);                                  \
    LGKM0();                                                                                   \
    MFMA8(0, bB[0], bB[1]);                                                                    \
  } while (0)

#define PPH4(T, DOSTG, DORD, VMN)                                                              \
  do {                                                                                         \
    if (DOSTG) PSTG_B((T) + 2);                                                                \
    VMN;                                                                                       \
    BAR();                                                                                     \
    if (DORD) {                                                                                \
      const u16* bn_ = lds + (((T) + 1) & 1) * 24576;                                          \
      _Pragma("unroll") for (int n = 0; n < 4; n++)                                            \
          bA[n] = *(const short8*)(bn_ + boff + n * 512);                                      \
    }                                                                                          \
    LGKM0();                                                                                   \
    MFMA8(2, bB[2], bB[3]);                                                                    \
  } while (0)

  PSTG_B(0); PSTG_ALO(0); PSTG_AHI(0); PSTG_B(1);
  VMWAIT(2);
  BAR();
  {
    const u16* bc_ = lds;
#pragma unroll
    for (int n = 0; n < 4; n++) bA[n] = *(const short8*)(bc_ + boff + n * 512);
  }

  for (int T = 0; T < 14; ++T) {
    PPH1(T, 1, VMWAIT(4));
    PPH2(T, 1);
    PPH3(T);
    PPH4(T, 1, 1, VMWAIT(6));
  }
  PPH1(14, 1, VMWAIT(4));
  PPH2(14, 1);
  PPH3(14);
  PPH4(14, 0, 1, VMWAIT(4));
  PPH1(15, 0, VMWAIT(0));
  PPH2(15, 0);
  PPH3(15);
  PPH4(15, 0, 0, (void)0);

#undef PPH1
#undef PPH2
#undef PPH3
#undef PPH4
#undef MFMA8
#undef PSTG_ALO
#undef PSTG_AHI
#undef PSTG_B

  int rbase = bm + wr * 64 + quad * 4;
  int cbase = bn + wc * 64 + l15;
#pragma unroll
  for (int m = 0; m < 4; m++)
#pragma unroll
    for (int n = 0; n < 4; n++)
#pragma unroll
      for (int r = 0; r < 4; r++)
        Co[(size_t)(rbase + m * 16 + r) * 1024 + cbase + n * 16] = acc[m][n][r];
}

// ---------------- flash attention (verified core; NEW: XCD-locality bh swizzle) -----
// Grid (64,8): the 8 strip-blocks sharing one bh's 512KB K/V previously landed on
// 8 different XCDs (linear id % 8). Remap bh = transpose8x8(x) so all 8 land on ONE
// XCD: 8 bh x 512KB = 4MB KV per XCD -> L2-resident re-reads. Pure bijection.
__global__ __launch_bounds__(256, 2) void attn_kernel(const u16* __restrict__ qbuf,
                                                      const u16* __restrict__ kpack,
                                                      const u16* __restrict__ vpack,
                                                      u16* __restrict__ ctx) {
  int t = threadIdx.x;
  int wave = t >> 6, lane = t & 63, l31 = lane & 31, hi = lane >> 5;
  int bhx = blockIdx.x;
  int bh = ((bhx & 7) << 3) | (bhx >> 3);  // 8x8 transpose: same-bh blocks -> same XCD
  int s = (int)blockIdx.y * 4 + wave;
  int b = bh >> 4, h = bh & 15;
  int rowbase = b * 2048;
  int hi4 = hi * 4;

  const u16* kp = kpack + (size_t)bh * (32 * 4096) + lane * 8;
  const u16* vp = vpack + (size_t)bh * (32 * 4096) + lane * 8;

#pragma unroll
  for (int ph = 0; ph < 2; ph++) {
    int strip = ph ? 63 - s : s;
    int q0 = strip * 32;
    int q_lane = q0 + l31;

    const u16* qp = qbuf + (size_t)(rowbase + q_lane) * 1024 + h * 64 + hi * 8;
    short8 qf[4];
#pragma unroll
    for (int ks = 0; ks < 4; ks++) qf[ks] = *(const short8*)(qp + ks * 16);

    float l_run = 0.0f;
    f32x16 o[2];
    o[0] = (f32x16)0.0f; o[1] = (f32x16)0.0f;
    int ktmax = (q0 + 31) >> 6;

    for (int kt = 0; kt <= ktmax; kt++) {
      const u16* kb = kp + kt * 4096;
      const u16* vb = vp + kt * 4096;

      short8 ka[8], vv[8];
#pragma unroll
      for (int j = 0; j < 8; j++) {
        ka[j] = *(const short8*)(kb + j * 512);
        vv[j] = *(const short8*)(vb + j * 512);
      }

      f32x16 st0 = (f32x16)0.0f, st1 = (f32x16)0.0f;
#pragma unroll
      for (int ks = 0; ks < 4; ks++) {
        st0 = __builtin_amdgcn_mfma_f32_32x32x16_bf16(ka[ks], qf[ks], st0, 0, 0, 0);
        st1 = __builtin_amdgcn_mfma_f32_32x32x16_bf16(ka[4 + ks], qf[ks], st1, 0, 0, 0);
      }

      unsigned pk[2][8];
      if (kt == ktmax) {
#pragma unroll
        for (int ii = 0; ii < 8; ii++) {
          int key = kt * 64 + ((2 * ii) & 3) + 8 * ((2 * ii) >> 2) + hi4;
          float p00 = (key     <= q_lane) ? __builtin_amdgcn_exp2f(st0[2 * ii])     : 0.0f;
          float p01 = (key + 1 <= q_lane) ? __builtin_amdgcn_exp2f(st0[2 * ii + 1]) : 0.0f;
          float p10 = (key + 32 <= q_lane) ? __builtin_amdgcn_exp2f(st1[2 * ii])     : 0.0f;
          float p11 = (key + 33 <= q_lane) ? __builtin_amdgcn_exp2f(st1[2 * ii + 1]) : 0.0f;
          l_run += p00 + p01 + p10 + p11;
          pk[0][ii] = ((__float_as_uint(p00) + 0x8000u) >> 16) |
                      ((__float_as_uint(p01) + 0x8000u) & 0xffff0000u);
          pk[1][ii] = ((__float_as_uint(p10) + 0x8000u) >> 16) |
                      ((__float_as_uint(p11) + 0x8000u) & 0xffff0000u);
        }
      } else {
#pragma unroll
        for (int ii = 0; ii < 8; ii++) {
          float p00 = __builtin_amdgcn_exp2f(st0[2 * ii]);
          float p01 = __builtin_amdgcn_exp2f(st0[2 * ii + 1]);
          float p10 = __builtin_amdgcn_exp2f(st1[2 * ii]);
          float p11 = __builtin_amdgcn_exp2f(st1[2 * ii + 1]);
          l_run += p00 + p01 + p10 + p11;
          pk[0][ii] = ((__float_as_uint(p00) + 0x8000u) >> 16) |
                      ((__float_as_uint(p01) + 0x8000u) & 0xffff0000u);
          pk[1][ii] = ((__float_as_uint(p10) + 0x8000u) >> 16) |
                      ((__float_as_uint(p11) + 0x8000u) & 0xffff0000u);
        }
      }

      short8 pf[4];
#pragma unroll
      for (int ks2 = 0; ks2 < 4; ks2++) {
        int km = ks2 >> 1, h4 = (ks2 & 1) * 4;
        unsigned A0 = pk[km][h4 + 0], A1 = pk[km][h4 + 1];
        unsigned B0 = pk[km][h4 + 2], B1 = pk[km][h4 + 3];
        unsigned tA0 = (unsigned)__shfl_xor((int)A0, 32);
        unsigned tA1 = (unsigned)__shfl_xor((int)A1, 32);
        unsigned tB0 = (unsigned)__shfl_xor((int)B0, 32);
        unsigned tB1 = (unsigned)__shfl_xor((int)B1, 32);
        union { unsigned u[4]; short8 sh; } fr;
        fr.u[0] = hi ? tB0 : A0;
        fr.u[1] = hi ? tB1 : A1;
        fr.u[2] = hi ? B0 : tA0;
        fr.u[3] = hi ? B1 : tA1;
        pf[ks2] = fr.sh;
      }

#pragma unroll
      for (int am = 0; am < 2; am++)
#pragma unroll
        for (int ks2 = 0; ks2 < 4; ks2++)
          o[am] = __builtin_amdgcn_mfma_f32_32x32x16_bf16(vv[am * 4 + ks2], pf[ks2], o[am], 0, 0, 0);
    }

    float l_tot = l_run + __shfl_xor(l_run, 32);
    float inv = 1.0f / l_tot;
    size_t obase = (size_t)(rowbase + q_lane) * 1024 + h * 64;
#pragma unroll
    for (int am = 0; am < 2; am++)
#pragma unroll
      for (int k = 0; k < 4; k++) {
        ushort4 w;
        w.x = f2bf(o[am][4 * k + 0] * inv);
        w.y = f2bf(o[am][4 * k + 1] * inv);
        w.z = f2bf(o[am][4 * k + 2] * inv);
        w.w = f2bf(o[am][4 * k + 3] * inv);
        *(ushort4*)&ctx[obase + am * 32 + k * 8 + hi4] = w;
      }
  }
}

// ---------------- launch ----------------
extern "C" void kernel_launch(void* const* d_in, const int* in_sizes, int n_in,
                              void* d_out, int out_size, void* d_ws, size_t ws_size,
                              hipStream_t stream) {
  const float* x      = (const float*)d_in[0];
  const float* w_qkv  = (const float*)d_in[1];
  const float* w_proj = (const float*)d_in[2];
  float* out = (float*)d_out;

  char* ws = (char*)d_ws;
  const size_t MB = 1024 * 1024;
  u16* qbuf   = (u16*)(ws);
  u16* kpack  = (u16*)(ws + 16 * MB);
  u16* vpack  = (u16*)(ws + 32 * MB);
  u16* xb     = (u16*)(ws + 48 * MB);
  u16* ctx    = (u16*)(ws + 64 * MB);
  u16* wqkvT  = (u16*)(ws + 80 * MB);
  u16* wprojT = (u16*)(ws + 86 * MB);

  prep_kernel<<<12288, 256, 0, stream>>>(x, xb, w_qkv, wqkvT, w_proj, wprojT);
  gemm_qkv<<<dim3(384), 512, 0, stream>>>(xb, wqkvT, qbuf, kpack, vpack);
  attn_kernel<<<dim3(64, 8), 256, 0, stream>>>(qbuf, kpack, vpack, ctx);
  gemm_proj<<<dim3(256), 512, 0, stream>>>(ctx, wprojT, out);
}